// Round 1
// baseline (854.443 us; speedup 1.0000x reference)
//
#include <hip/hip_runtime.h>
#include <math.h>

#define HD 128
#define WD 128
#define BB 32
#define KK 32
#define NPIX (BB*HD*WD)   // 524288

// ---------------- fused CNN: one-hot -> conv3x3(10->32)+relu -> conv3x3(32->32)+relu -> conv1x1(32->32) ----------
// tile 16 rows x 32 cols, 512 threads, x1 staged in LDS ic-major (conflict-free conv2 reads)
#define TH 16
#define TW 32
#define X1H (TH+2)   // 18
#define X1W (TW+2)   // 34
#define XTH (TH+4)   // 20
#define XTW (TW+4)   // 36

__global__ __launch_bounds__(512) void cnn_kernel(
    const int* __restrict__ X,
    const float* __restrict__ w1, const float* __restrict__ b1,
    const float* __restrict__ w2, const float* __restrict__ b2,
    const float* __restrict__ w3, const float* __restrict__ b3,
    float* __restrict__ phi)
{
  __shared__ float sW1[9*11*32];       // class 10 = zero pad (OOB one-hot)
  __shared__ float sW2[9*32*32];
  __shared__ float sW3[32*32];
  __shared__ float sB1[32], sB2[32], sB3[32];
  __shared__ int   sX[XTH*XTW];
  __shared__ float sX1[32][X1H*X1W];   // ic-major

  const int tid = threadIdx.x;
  const int b   = blockIdx.z;
  const int bh0 = blockIdx.y * TH;
  const int bw0 = blockIdx.x * TW;

  for (int i = tid; i < 9*11*32; i += 512) {
    int oc = i & 31, c = (i >> 5) % 11, tap = i / (11*32);
    sW1[i] = (c < 10) ? w1[(tap*10 + c)*32 + oc] : 0.f;
  }
  for (int i = tid; i < 9*32*32; i += 512) sW2[i] = w2[i];
  for (int i = tid; i < 32*32;   i += 512) sW3[i] = w3[i];
  if (tid < 32) { sB1[tid] = b1[tid]; sB2[tid] = b2[tid]; sB3[tid] = b3[tid]; }
  for (int i = tid; i < XTH*XTW; i += 512) {
    int ti = i / XTW, tj = i % XTW;
    int gh = bh0 - 2 + ti, gw = bw0 - 2 + tj;
    sX[i] = (gh >= 0 && gh < HD && gw >= 0 && gw < WD) ? X[(b*HD + gh)*WD + gw] : 10;
  }
  __syncthreads();

  // conv1: pure gather of w1 rows by class (input is one-hot), + relu
  for (int p = tid; p < X1H*X1W; p += 512) {
    int ti = p / X1W, tj = p % X1W;
    int gh = bh0 - 1 + ti, gw = bw0 - 1 + tj;
    float acc[32];
    if (gh >= 0 && gh < HD && gw >= 0 && gw < WD) {
      #pragma unroll
      for (int oc = 0; oc < 32; oc++) acc[oc] = sB1[oc];
      #pragma unroll
      for (int di = 0; di < 3; di++)
      #pragma unroll
      for (int dj = 0; dj < 3; dj++) {
        int c = sX[(ti+di)*XTW + (tj+dj)];
        const float* wr = &sW1[((di*3+dj)*11 + c)*32];
        #pragma unroll
        for (int oc = 0; oc < 32; oc++) acc[oc] += wr[oc];
      }
      #pragma unroll
      for (int oc = 0; oc < 32; oc++) acc[oc] = fmaxf(acc[oc], 0.f);
    } else {
      #pragma unroll
      for (int oc = 0; oc < 32; oc++) acc[oc] = 0.f;
    }
    #pragma unroll
    for (int oc = 0; oc < 32; oc++) sX1[oc][p] = acc[oc];
  }
  __syncthreads();

  // conv2 (+relu) + conv1x1, one output pixel per thread
  const int i = tid >> 5, j = tid & 31;
  float acc2[32];
  #pragma unroll
  for (int oc = 0; oc < 32; oc++) acc2[oc] = sB2[oc];
  #pragma unroll 1
  for (int di = 0; di < 3; di++)
  #pragma unroll 1
  for (int dj = 0; dj < 3; dj++) {
    const int pp = (i+di)*X1W + (j+dj);
    const float* w2t = &sW2[(di*3+dj)*1024];
    #pragma unroll
    for (int ic = 0; ic < 32; ic++) {
      float s = sX1[ic][pp];
      #pragma unroll
      for (int oc = 0; oc < 32; oc++) acc2[oc] = fmaf(s, w2t[ic*32 + oc], acc2[oc]);
    }
  }
  float acc3[32];
  #pragma unroll
  for (int oe = 0; oe < 32; oe++) acc3[oe] = sB3[oe];
  #pragma unroll
  for (int ic = 0; ic < 32; ic++) {
    float s = fmaxf(acc2[ic], 0.f);
    #pragma unroll
    for (int oe = 0; oe < 32; oe++) acc3[oe] = fmaf(s, sW3[ic*32 + oe], acc3[oe]);
  }
  float* dst = phi + ((size_t)((b*HD + bh0 + i)*WD + bw0 + j))*32;
  #pragma unroll
  for (int q = 0; q < 8; q++)
    ((float4*)dst)[q] = make_float4(acc3[4*q], acc3[4*q+1], acc3[4*q+2], acc3[4*q+3]);
}

// ---------------- neighbor affinity: w[...,d] = exp(-2*||phi - phi_nb||^2) * valid ----------------
__device__ __forceinline__ float aff_one(const float* __restrict__ nb, const float* c, bool valid) {
  if (!valid) return 0.f;
  float d2 = 0.f;
  #pragma unroll
  for (int q = 0; q < 8; q++) {
    float4 v = ((const float4*)nb)[q];
    float e0 = c[4*q]   - v.x;
    float e1 = c[4*q+1] - v.y;
    float e2 = c[4*q+2] - v.z;
    float e3 = c[4*q+3] - v.w;
    d2 = fmaf(e0,e0, fmaf(e1,e1, fmaf(e2,e2, fmaf(e3,e3, d2))));
  }
  return __expf(-2.f * d2);
}

__global__ __launch_bounds__(256) void aff_kernel(const float* __restrict__ phi, float* __restrict__ wb) {
  const int t = blockIdx.x * 256 + threadIdx.x;
  const int w = t & (WD-1), h = (t >> 7) & (HD-1);
  const float* pc = phi + (size_t)t * 32;
  float c[32];
  #pragma unroll
  for (int q = 0; q < 8; q++) {
    float4 v = ((const float4*)pc)[q];
    c[4*q]=v.x; c[4*q+1]=v.y; c[4*q+2]=v.z; c[4*q+3]=v.w;
  }
  float4 out;
  out.x = aff_one(pc + WD*32, c, h < HD-1);  // shift(-1,0): phi[h+1,w]
  out.y = aff_one(pc - WD*32, c, h > 0);     // shift( 1,0): phi[h-1,w]
  out.z = aff_one(pc + 32,    c, w < WD-1);  // shift(0,-1): phi[h,w+1]
  out.w = aff_one(pc - 32,    c, w > 0);     // shift(0, 1): phi[h,w-1]
  ((float4*)wb)[t] = out;
}

// ---------------- analytic seed init: A0 = softmax_k(-d2/512) ----------------
__global__ __launch_bounds__(256) void init_kernel(float* __restrict__ A) {
  const int t = blockIdx.x * 256 + threadIdx.x;
  const int w = t & (WD-1), h = (t >> 7) & (HD-1);
  const float fh = (float)h, fw = (float)w;
  float v[32]; float m = -1e30f;
  #pragma unroll
  for (int k = 0; k < 32; k++) {
    float dh = fh - (float)((k >> 3)*32 + 16);
    float dw = fw - (float)((k & 7)*16 + 8);
    float x = -(dh*dh + dw*dw) * (1.f/512.f);
    v[k] = x; m = fmaxf(m, x);
  }
  float s = 0.f;
  #pragma unroll
  for (int k = 0; k < 32; k++) { v[k] = __expf(v[k] - m); s += v[k]; }
  float inv = 1.f / s;
  float* dst = A + (size_t)t*32;
  #pragma unroll
  for (int q = 0; q < 8; q++)
    ((float4*)dst)[q] = make_float4(v[4*q]*inv, v[4*q+1]*inv, v[4*q+2]*inv, v[4*q+3]*inv);
}

// ---------------- one message-pass iteration: A = softmax_k(2 * sum_d w_d * A_shift_d) ----------------
__device__ __forceinline__ void acc_nb(float* a, const float* __restrict__ src, float wt) {
  #pragma unroll
  for (int q = 0; q < 8; q++) {
    float4 v = ((const float4*)src)[q];
    a[4*q]   = fmaf(wt, v.x, a[4*q]);
    a[4*q+1] = fmaf(wt, v.y, a[4*q+1]);
    a[4*q+2] = fmaf(wt, v.z, a[4*q+2]);
    a[4*q+3] = fmaf(wt, v.w, a[4*q+3]);
  }
}

__global__ __launch_bounds__(256) void mp_kernel(const float* __restrict__ Ain,
                                                 const float* __restrict__ wb,
                                                 float* __restrict__ Aout) {
  const int t = blockIdx.x * 256 + threadIdx.x;
  const int w = t & (WD-1), h = (t >> 7) & (HD-1);
  float4 wd = ((const float4*)wb)[t];
  float a[32];
  #pragma unroll
  for (int k = 0; k < 32; k++) a[k] = 0.f;
  if (h < HD-1) acc_nb(a, Ain + (size_t)(t + WD)*32, wd.x);
  if (h > 0)    acc_nb(a, Ain + (size_t)(t - WD)*32, wd.y);
  if (w < WD-1) acc_nb(a, Ain + (size_t)(t + 1)*32,  wd.z);
  if (w > 0)    acc_nb(a, Ain + (size_t)(t - 1)*32,  wd.w);
  float m = -1e30f;
  #pragma unroll
  for (int k = 0; k < 32; k++) { a[k] *= 2.f; m = fmaxf(m, a[k]); }
  float s = 0.f;
  #pragma unroll
  for (int k = 0; k < 32; k++) { a[k] = __expf(a[k] - m); s += a[k]; }
  float inv = 1.f / s;
  float* dst = Aout + (size_t)t*32;
  #pragma unroll
  for (int q = 0; q < 8; q++)
    ((float4*)dst)[q] = make_float4(a[4*q]*inv, a[4*q+1]*inv, a[4*q+2]*inv, a[4*q+3]*inv);
}

// ---------------- pooled features, stage 1: per-(b, 8-row chunk) partial sums ----------------
// partials layout: part[b][chunk][k][15] ; fields: s0, sh, sw, sh2, sw2, col[10]
__global__ __launch_bounds__(256) void pool1_kernel(const float* __restrict__ A,
                                                    const int* __restrict__ X,
                                                    float* __restrict__ part) {
  const int b = blockIdx.x, chunk = blockIdx.y;
  const int k = threadIdx.x & 31, sub = threadIdx.x >> 5;   // 8 rows per chunk
  const int h = chunk*8 + sub;
  const float hh = ((float)h + 0.5f) * (1.f/128.f);
  float s0 = 0.f, sw = 0.f, sw2 = 0.f;
  float col[10];
  #pragma unroll
  for (int c = 0; c < 10; c++) col[c] = 0.f;
  const float* Arow = A + ((size_t)(b*HD + h)*WD)*32 + k;
  const int*   Xrow = X + (b*HD + h)*WD;
  for (int w = 0; w < WD; w++) {
    float a  = Arow[(size_t)w*32];
    float ww = ((float)w + 0.5f) * (1.f/128.f);
    s0 += a; sw = fmaf(ww, a, sw); sw2 = fmaf(ww*ww, a, sw2);
    int x = Xrow[w];
    #pragma unroll
    for (int c = 0; c < 10; c++) col[c] += (x == c) ? a : 0.f;
  }
  __shared__ float red[8][32][15];
  float vals[15];
  vals[0] = s0; vals[1] = hh*s0; vals[2] = sw; vals[3] = hh*hh*s0; vals[4] = sw2;
  #pragma unroll
  for (int c = 0; c < 10; c++) vals[5+c] = col[c];
  #pragma unroll
  for (int q = 0; q < 15; q++) red[sub][k][q] = vals[q];
  __syncthreads();
  if (sub == 0) {
    #pragma unroll
    for (int q = 0; q < 15; q++) {
      float v = 0.f;
      #pragma unroll
      for (int s2 = 0; s2 < 8; s2++) v += red[s2][k][q];
      part[(((size_t)b*16 + chunk)*32 + k)*15 + q] = v;
    }
  }
}

// ---------------- pooled features, stage 2: finish T (B,K,17) ----------------
__global__ __launch_bounds__(256) void pool2_kernel(const float* __restrict__ part,
                                                    float* __restrict__ T) {
  const int t = blockIdx.x * 256 + threadIdx.x;
  if (t >= BB*KK) return;
  const int b = t >> 5, k = t & 31;
  float s[15];
  #pragma unroll
  for (int q = 0; q < 15; q++) s[q] = 0.f;
  for (int chunk = 0; chunk < 16; chunk++) {
    const float* p = part + (((size_t)b*16 + chunk)*32 + k)*15;
    #pragma unroll
    for (int q = 0; q < 15; q++) s[q] += p[q];
  }
  float mass = s[0] + 1e-6f;
  float inv  = 1.f / mass;
  float h_c = s[1]*inv, w_c = s[2]*inv, h2 = s[3]*inv, w2 = s[4]*inv;
  float h_sd = sqrtf(fmaxf(h2 - h_c*h_c, 0.f) + 1e-6f);
  float w_sd = sqrtf(fmaxf(w2 - w_c*w_c, 0.f) + 1e-6f);
  float* o = T + (size_t)t*17;
  o[0] = mass * (1.f/16384.f);
  o[1] = h_c; o[2] = w_c;
  #pragma unroll
  for (int c = 0; c < 10; c++) o[3+c] = s[5+c]*inv;
  o[13] = h_c - h_sd; o[14] = h_c + h_sd; o[15] = w_c - w_sd; o[16] = w_c + w_sd;
}

extern "C" void kernel_launch(void* const* d_in, const int* in_sizes, int n_in,
                              void* d_out, int out_size, void* d_ws, size_t ws_size,
                              hipStream_t stream) {
  const int*   X  = (const int*)d_in[0];
  const float* w1 = (const float*)d_in[1];
  const float* b1 = (const float*)d_in[2];
  const float* w2 = (const float*)d_in[3];
  const float* b2 = (const float*)d_in[4];
  const float* w3 = (const float*)d_in[5];
  const float* b3 = (const float*)d_in[6];

  float* out   = (float*)d_out;
  float* A_out = out;                           // (B,H,W,K)  64 MB, also ping-pong slot
  float* T_out = out + (size_t)NPIX * KK;       // (B,K,17)

  float* phi  = (float*)d_ws;                   // (B,H,W,32) 64 MB, later reused as A-ping
  float* wb   = phi + (size_t)NPIX * 32;        // (B,H,W,4)   8 MB
  float* part = wb  + (size_t)NPIX * 4;         // (B,16,K,15) ~1 MB

  cnn_kernel<<<dim3(WD/TW, HD/TH, BB), 512, 0, stream>>>(X, w1, b1, w2, b2, w3, b3, phi);
  aff_kernel<<<NPIX/256, 256, 0, stream>>>(phi, wb);
  init_kernel<<<NPIX/256, 256, 0, stream>>>(A_out);
  float* Aping = phi;  // phi dead after aff_kernel
  for (int it = 0; it < 4; it++) {
    mp_kernel<<<NPIX/256, 256, 0, stream>>>(A_out, wb, Aping);
    mp_kernel<<<NPIX/256, 256, 0, stream>>>(Aping, wb, A_out);
  }
  pool1_kernel<<<dim3(BB, 16), 256, 0, stream>>>(A_out, X, part);
  pool2_kernel<<<(BB*KK + 255)/256, 256, 0, stream>>>(part, T_out);
}

// Round 2
// 662.841 us; speedup vs baseline: 1.2891x; 1.2891x over previous
//
#include <hip/hip_runtime.h>
#include <math.h>

#define HD 128
#define WD 128
#define BB 32
#define KK 32
#define NPIX (BB*HD*WD)   // 524288

typedef __attribute__((ext_vector_type(8))) short bf16x8;
typedef __attribute__((ext_vector_type(4))) float f32x4;

__device__ __forceinline__ unsigned short f2bf(float x){
  unsigned u = __float_as_uint(x);
  u += 0x7FFFu + ((u >> 16) & 1u);
  return (unsigned short)(u >> 16);
}
__device__ __forceinline__ float bf2f(unsigned short h){
  return __uint_as_float(((unsigned)h) << 16);
}
// byte offset of 16B chunk kg within row, 64B rows, 2-bit XOR window swizzle
__device__ __forceinline__ int swz(int row, int kg){
  return row*64 + ((kg ^ (row & 3)) << 4);
}

// ---------------- fused CNN via MFMA (bf16 hi/lo split, fp32 accumulate) ----------------
// tile 16 rows x 32 cols, 512 threads (8 waves), halo x1 18x34
__global__ __launch_bounds__(512, 1) void cnn_kernel(
    const int* __restrict__ X,
    const float* __restrict__ w1, const float* __restrict__ b1,
    const float* __restrict__ w2, const float* __restrict__ b2,
    const float* __restrict__ w3, const float* __restrict__ b3,
    float* __restrict__ phi)
{
  __shared__ float sW1[9*11*36];     // [tap][class(11; 10=zero pad)][36-padded oc]
  __shared__ int   sX[20*36];
  __shared__ float sB1[32], sB2[32], sB3[32];
  __shared__ short x1h[612*32];      // halo 18x34 rows x 32 ic (bf16 hi), swizzled; reused as y2h
  __shared__ short x1l[612*32];      // bf16 lo; reused as y2l
  __shared__ short w2th[9*32*32];    // [tap*32+oc][ic] bf16 hi, swizzled
  __shared__ short w2tl[9*32*32];
  __shared__ short w3th[32*32];      // [oe][ic]
  __shared__ short w3tl[32*32];

  const int tid = threadIdx.x;
  const int img = blockIdx.z;
  const int bh0 = blockIdx.y * 16;
  const int bw0 = blockIdx.x * 32;

  // ---- stage weights / classes ----
  for (int i = tid; i < 9*11*32; i += 512) {
    int tap = i / 352, c = (i % 352) >> 5, oc = i & 31;
    sW1[(tap*11 + c)*36 + oc] = (c < 10) ? w1[tap*320 + c*32 + oc] : 0.f;
  }
  for (int i = tid; i < 9*32*32; i += 512) {
    int tap = i >> 10, ic = (i >> 5) & 31, oc = i & 31;
    float v = w2[i];
    unsigned short h = f2bf(v);
    unsigned short l = f2bf(v - bf2f(h));
    int row = tap*32 + oc;
    int off = swz(row, ic >> 3) + (ic & 7)*2;
    *(unsigned short*)((char*)w2th + off) = h;
    *(unsigned short*)((char*)w2tl + off) = l;
  }
  for (int i = tid; i < 32*32; i += 512) {
    int ic = i >> 5, oe = i & 31;
    float v = w3[i];
    unsigned short h = f2bf(v);
    unsigned short l = f2bf(v - bf2f(h));
    int off = swz(oe, ic >> 3) + (ic & 7)*2;
    *(unsigned short*)((char*)w3th + off) = h;
    *(unsigned short*)((char*)w3tl + off) = l;
  }
  if (tid < 32) { sB1[tid] = b1[tid]; sB2[tid] = b2[tid]; sB3[tid] = b3[tid]; }
  for (int i = tid; i < 20*36; i += 512) {
    int ti = i / 36, tj = i % 36;
    int gh = bh0 - 2 + ti, gw = bw0 - 2 + tj;
    sX[i] = (gh >= 0 && gh < HD && gw >= 0 && gw < WD) ? X[(img*HD + gh)*WD + gw] : 10;
  }
  __syncthreads();

  // ---- conv1: class-gather (exact fp32) -> relu -> bf16 hi/lo into x1 ----
  for (int p = tid; p < 612; p += 512) {
    int hr = p / 34, hc = p - hr*34;
    int gh = bh0 + hr - 1, gw = bw0 + hc - 1;
    if (gh >= 0 && gh < HD && gw >= 0 && gw < WD) {
      float a[32];
      #pragma unroll
      for (int g = 0; g < 8; g++) {
        float4 v = ((const float4*)sB1)[g];
        a[4*g] = v.x; a[4*g+1] = v.y; a[4*g+2] = v.z; a[4*g+3] = v.w;
      }
      #pragma unroll
      for (int tap = 0; tap < 9; tap++) {
        const int ti = tap/3, tj = tap%3;
        int c = sX[(hr+ti)*36 + hc + tj];
        const float4* wr = (const float4*)&sW1[(tap*11 + c)*36];
        #pragma unroll
        for (int g = 0; g < 8; g++) {
          float4 v = wr[g];
          a[4*g] += v.x; a[4*g+1] += v.y; a[4*g+2] += v.z; a[4*g+3] += v.w;
        }
      }
      #pragma unroll
      for (int g = 0; g < 4; g++) {
        bf16x8 hv, lv;
        #pragma unroll
        for (int j = 0; j < 8; j++) {
          float v = fmaxf(a[g*8+j], 0.f);
          unsigned short h = f2bf(v);
          unsigned short l = f2bf(v - bf2f(h));
          hv[j] = (short)h; lv[j] = (short)l;
        }
        int off = swz(p, g);
        *(bf16x8*)((char*)x1h + off) = hv;
        *(bf16x8*)((char*)x1l + off) = lv;
      }
    } else {
      bf16x8 z;
      #pragma unroll
      for (int j = 0; j < 8; j++) z[j] = 0;
      #pragma unroll
      for (int g = 0; g < 4; g++) {
        int off = swz(p, g);
        *(bf16x8*)((char*)x1h + off) = z;
        *(bf16x8*)((char*)x1l + off) = z;
      }
    }
  }
  __syncthreads();

  // ---- conv2 via MFMA: D[px][oc] = sum_tap,ic x1[px+tap][ic]*w2[tap][ic][oc] ----
  const int lane = tid & 63;
  const int wv   = tid >> 6;       // 0..7
  const int lr   = lane & 15;
  const int kg   = lane >> 4;      // 0..3
  const int mts  = wv * 4;

  int arow0[4];
  #pragma unroll
  for (int q = 0; q < 4; q++) {
    int px = (mts + q)*16 + lr;
    arow0[q] = (px >> 5)*34 + (px & 31);   // halo row index at tap (0,0)
  }
  float b2v0 = sB2[lr], b2v1 = sB2[lr + 16];
  f32x4 acc[4][2];
  #pragma unroll
  for (int q = 0; q < 4; q++) {
    acc[q][0] = (f32x4){b2v0, b2v0, b2v0, b2v0};
    acc[q][1] = (f32x4){b2v1, b2v1, b2v1, b2v1};
  }

  #pragma unroll
  for (int tap = 0; tap < 9; tap++) {
    const int ti = tap/3, tj = tap%3;
    int rb0 = tap*32 + lr, rb1 = rb0 + 16;
    int ob0 = swz(rb0, kg), ob1 = swz(rb1, kg);
    bf16x8 bh0 = *(const bf16x8*)((const char*)w2th + ob0);
    bf16x8 bl0 = *(const bf16x8*)((const char*)w2tl + ob0);
    bf16x8 bh1 = *(const bf16x8*)((const char*)w2th + ob1);
    bf16x8 bl1 = *(const bf16x8*)((const char*)w2tl + ob1);
    #pragma unroll
    for (int q = 0; q < 4; q++) {
      int row = arow0[q] + ti*34 + tj;
      int off = swz(row, kg);
      bf16x8 ah = *(const bf16x8*)((const char*)x1h + off);
      bf16x8 al = *(const bf16x8*)((const char*)x1l + off);
      acc[q][0] = __builtin_amdgcn_mfma_f32_16x16x32_bf16(ah, bh0, acc[q][0], 0, 0, 0);
      acc[q][0] = __builtin_amdgcn_mfma_f32_16x16x32_bf16(al, bh0, acc[q][0], 0, 0, 0);
      acc[q][0] = __builtin_amdgcn_mfma_f32_16x16x32_bf16(ah, bl0, acc[q][0], 0, 0, 0);
      acc[q][1] = __builtin_amdgcn_mfma_f32_16x16x32_bf16(ah, bh1, acc[q][1], 0, 0, 0);
      acc[q][1] = __builtin_amdgcn_mfma_f32_16x16x32_bf16(al, bh1, acc[q][1], 0, 0, 0);
      acc[q][1] = __builtin_amdgcn_mfma_f32_16x16x32_bf16(ah, bl1, acc[q][1], 0, 0, 0);
    }
  }
  __syncthreads();

  // ---- relu + split -> y2 (reusing x1 buffers, rows 0..511) ----
  #pragma unroll
  for (int q = 0; q < 4; q++) {
    #pragma unroll
    for (int nt = 0; nt < 2; nt++) {
      int oc = nt*16 + lr;
      #pragma unroll
      for (int rg = 0; rg < 4; rg++) {
        int px = (mts + q)*16 + kg*4 + rg;
        float v = fmaxf(acc[q][nt][rg], 0.f);
        unsigned short h = f2bf(v);
        unsigned short l = f2bf(v - bf2f(h));
        int off = swz(px, oc >> 3) + (oc & 7)*2;
        *(unsigned short*)((char*)x1h + off) = h;
        *(unsigned short*)((char*)x1l + off) = l;
      }
    }
  }
  __syncthreads();

  // ---- conv3 via MFMA (K=32) + write phi ----
  {
    int ob0 = swz(lr, kg), ob1 = swz(lr + 16, kg);
    bf16x8 ch0 = *(const bf16x8*)((const char*)w3th + ob0);
    bf16x8 cl0 = *(const bf16x8*)((const char*)w3tl + ob0);
    bf16x8 ch1 = *(const bf16x8*)((const char*)w3th + ob1);
    bf16x8 cl1 = *(const bf16x8*)((const char*)w3tl + ob1);
    float b3v0 = sB3[lr], b3v1 = sB3[lr + 16];
    #pragma unroll
    for (int q = 0; q < 4; q++) {
      int row = (mts + q)*16 + lr;
      int off = swz(row, kg);
      bf16x8 ah = *(const bf16x8*)((const char*)x1h + off);
      bf16x8 al = *(const bf16x8*)((const char*)x1l + off);
      f32x4 o0 = (f32x4){b3v0, b3v0, b3v0, b3v0};
      f32x4 o1 = (f32x4){b3v1, b3v1, b3v1, b3v1};
      o0 = __builtin_amdgcn_mfma_f32_16x16x32_bf16(ah, ch0, o0, 0, 0, 0);
      o0 = __builtin_amdgcn_mfma_f32_16x16x32_bf16(al, ch0, o0, 0, 0, 0);
      o0 = __builtin_amdgcn_mfma_f32_16x16x32_bf16(ah, cl0, o0, 0, 0, 0);
      o1 = __builtin_amdgcn_mfma_f32_16x16x32_bf16(ah, ch1, o1, 0, 0, 0);
      o1 = __builtin_amdgcn_mfma_f32_16x16x32_bf16(al, ch1, o1, 0, 0, 0);
      o1 = __builtin_amdgcn_mfma_f32_16x16x32_bf16(ah, cl1, o1, 0, 0, 0);
      #pragma unroll
      for (int rg = 0; rg < 4; rg++) {
        int px = (mts + q)*16 + kg*4 + rg;
        int gh = bh0 + (px >> 5), gw = bw0 + (px & 31);
        float* dst = phi + ((size_t)((img*HD + gh)*WD + gw))*32;
        dst[lr]      = o0[rg];
        dst[lr + 16] = o1[rg];
      }
    }
  }
}

// ---------------- neighbor affinity ----------------
__device__ __forceinline__ float aff_one(const float* __restrict__ nb, const float* c, bool valid) {
  if (!valid) return 0.f;
  float d2 = 0.f;
  #pragma unroll
  for (int q = 0; q < 8; q++) {
    float4 v = ((const float4*)nb)[q];
    float e0 = c[4*q]   - v.x;
    float e1 = c[4*q+1] - v.y;
    float e2 = c[4*q+2] - v.z;
    float e3 = c[4*q+3] - v.w;
    d2 = fmaf(e0,e0, fmaf(e1,e1, fmaf(e2,e2, fmaf(e3,e3, d2))));
  }
  return __expf(-2.f * d2);
}

__global__ __launch_bounds__(256) void aff_kernel(const float* __restrict__ phi, float* __restrict__ wb) {
  const int t = blockIdx.x * 256 + threadIdx.x;
  const int w = t & (WD-1), h = (t >> 7) & (HD-1);
  const float* pc = phi + (size_t)t * 32;
  float c[32];
  #pragma unroll
  for (int q = 0; q < 8; q++) {
    float4 v = ((const float4*)pc)[q];
    c[4*q]=v.x; c[4*q+1]=v.y; c[4*q+2]=v.z; c[4*q+3]=v.w;
  }
  float4 out;
  out.x = aff_one(pc + WD*32, c, h < HD-1);
  out.y = aff_one(pc - WD*32, c, h > 0);
  out.z = aff_one(pc + 32,    c, w < WD-1);
  out.w = aff_one(pc - 32,    c, w > 0);
  ((float4*)wb)[t] = out;
}

// ---------------- message pass (XCD-swizzled; FIRST computes analytic A0 neighbors) ----------------
__device__ __forceinline__ void acc_nb(float* a, const float* __restrict__ src, float wt) {
  #pragma unroll
  for (int q = 0; q < 8; q++) {
    float4 v = ((const float4*)src)[q];
    a[4*q]   = fmaf(wt, v.x, a[4*q]);
    a[4*q+1] = fmaf(wt, v.y, a[4*q+1]);
    a[4*q+2] = fmaf(wt, v.z, a[4*q+2]);
    a[4*q+3] = fmaf(wt, v.w, a[4*q+3]);
  }
}

template<int FIRST>
__global__ __launch_bounds__(256) void mp_kernel(const float* __restrict__ Ain,
                                                 const float* __restrict__ wb,
                                                 float* __restrict__ Aout) {
  const int blk  = blockIdx.x;                  // 2048 blocks
  const int sblk = (blk & 7) * 256 + (blk >> 3);  // 256 contiguous blocks per XCD
  const int t = sblk * 256 + threadIdx.x;
  const int w = t & (WD-1), h = (t >> 7) & (HD-1);
  float4 wd = ((const float4*)wb)[t];
  float a[32];
  #pragma unroll
  for (int k = 0; k < 32; k++) a[k] = 0.f;

  if (FIRST) {
    int hs[4]; int ws_[4]; float wgt[4];
    hs[0] = (h < HD-1) ? h+1 : h;  ws_[0] = w;                  wgt[0] = wd.x;
    hs[1] = (h > 0)    ? h-1 : h;  ws_[1] = w;                  wgt[1] = wd.y;
    hs[2] = h;                     ws_[2] = (w < WD-1) ? w+1 : w; wgt[2] = wd.z;
    hs[3] = h;                     ws_[3] = (w > 0)    ? w-1 : w; wgt[3] = wd.w;
    #pragma unroll
    for (int d = 0; d < 4; d++) {
      float fh = (float)hs[d], fw = (float)ws_[d];
      float e[32]; float m = -1e30f;
      #pragma unroll
      for (int kh = 0; kh < 4; kh++) {
        float dh = fh - (float)(kh*32 + 16);
        float dh2 = dh*dh;
        #pragma unroll
        for (int kw = 0; kw < 8; kw++) {
          float dw = fw - (float)(kw*16 + 8);
          float x = -(dh2 + dw*dw) * (1.f/512.f);
          e[kh*8+kw] = x; m = fmaxf(m, x);
        }
      }
      float s = 0.f;
      #pragma unroll
      for (int k = 0; k < 32; k++) { e[k] = __expf(e[k] - m); s += e[k]; }
      float sc = wgt[d] / s;
      #pragma unroll
      for (int k = 0; k < 32; k++) a[k] = fmaf(e[k], sc, a[k]);
    }
  } else {
    int tu = (h < HD-1) ? t + WD : t;
    int td = (h > 0)    ? t - WD : t;
    int tl = (w < WD-1) ? t + 1  : t;
    int tr = (w > 0)    ? t - 1  : t;
    acc_nb(a, Ain + (size_t)tu*32, wd.x);
    acc_nb(a, Ain + (size_t)td*32, wd.y);
    acc_nb(a, Ain + (size_t)tl*32, wd.z);
    acc_nb(a, Ain + (size_t)tr*32, wd.w);
  }

  float m = -1e30f;
  #pragma unroll
  for (int k = 0; k < 32; k++) { a[k] *= 2.f; m = fmaxf(m, a[k]); }
  float s = 0.f;
  #pragma unroll
  for (int k = 0; k < 32; k++) { a[k] = __expf(a[k] - m); s += a[k]; }
  float inv = 1.f / s;
  float* dst = Aout + (size_t)t*32;
  #pragma unroll
  for (int q = 0; q < 8; q++)
    ((float4*)dst)[q] = make_float4(a[4*q]*inv, a[4*q+1]*inv, a[4*q+2]*inv, a[4*q+3]*inv);
}

// ---------------- pooled features, stage 1 ----------------
__global__ __launch_bounds__(256) void pool1_kernel(const float* __restrict__ A,
                                                    const int* __restrict__ X,
                                                    float* __restrict__ part) {
  const int b = blockIdx.x, chunk = blockIdx.y;
  const int k = threadIdx.x & 31, sub = threadIdx.x >> 5;
  const int h = chunk*8 + sub;
  const float hh = ((float)h + 0.5f) * (1.f/128.f);
  float s0 = 0.f, sw = 0.f, sw2 = 0.f;
  float col[10];
  #pragma unroll
  for (int c = 0; c < 10; c++) col[c] = 0.f;
  const float* Arow = A + ((size_t)(b*HD + h)*WD)*32 + k;
  const int*   Xrow = X + (b*HD + h)*WD;
  for (int w = 0; w < WD; w++) {
    float a  = Arow[(size_t)w*32];
    float ww = ((float)w + 0.5f) * (1.f/128.f);
    s0 += a; sw = fmaf(ww, a, sw); sw2 = fmaf(ww*ww, a, sw2);
    int x = Xrow[w];
    #pragma unroll
    for (int c = 0; c < 10; c++) col[c] += (x == c) ? a : 0.f;
  }
  __shared__ float red[8][32][15];
  float vals[15];
  vals[0] = s0; vals[1] = hh*s0; vals[2] = sw; vals[3] = hh*hh*s0; vals[4] = sw2;
  #pragma unroll
  for (int c = 0; c < 10; c++) vals[5+c] = col[c];
  #pragma unroll
  for (int q = 0; q < 15; q++) red[sub][k][q] = vals[q];
  __syncthreads();
  if (sub == 0) {
    #pragma unroll
    for (int q = 0; q < 15; q++) {
      float v = 0.f;
      #pragma unroll
      for (int s2 = 0; s2 < 8; s2++) v += red[s2][k][q];
      part[(((size_t)b*16 + chunk)*32 + k)*15 + q] = v;
    }
  }
}

// ---------------- pooled features, stage 2 ----------------
__global__ __launch_bounds__(256) void pool2_kernel(const float* __restrict__ part,
                                                    float* __restrict__ T) {
  const int t = blockIdx.x * 256 + threadIdx.x;
  if (t >= BB*KK) return;
  float s[15];
  #pragma unroll
  for (int q = 0; q < 15; q++) s[q] = 0.f;
  const int b = t >> 5, k = t & 31;
  for (int chunk = 0; chunk < 16; chunk++) {
    const float* p = part + (((size_t)b*16 + chunk)*32 + k)*15;
    #pragma unroll
    for (int q = 0; q < 15; q++) s[q] += p[q];
  }
  float mass = s[0] + 1e-6f;
  float inv  = 1.f / mass;
  float h_c = s[1]*inv, w_c = s[2]*inv, h2 = s[3]*inv, w2 = s[4]*inv;
  float h_sd = sqrtf(fmaxf(h2 - h_c*h_c, 0.f) + 1e-6f);
  float w_sd = sqrtf(fmaxf(w2 - w_c*w_c, 0.f) + 1e-6f);
  float* o = T + (size_t)t*17;
  o[0] = mass * (1.f/16384.f);
  o[1] = h_c; o[2] = w_c;
  #pragma unroll
  for (int c = 0; c < 10; c++) o[3+c] = s[5+c]*inv;
  o[13] = h_c - h_sd; o[14] = h_c + h_sd; o[15] = w_c - w_sd; o[16] = w_c + w_sd;
}

extern "C" void kernel_launch(void* const* d_in, const int* in_sizes, int n_in,
                              void* d_out, int out_size, void* d_ws, size_t ws_size,
                              hipStream_t stream) {
  const int*   X  = (const int*)d_in[0];
  const float* w1 = (const float*)d_in[1];
  const float* b1 = (const float*)d_in[2];
  const float* w2 = (const float*)d_in[3];
  const float* b2 = (const float*)d_in[4];
  const float* w3 = (const float*)d_in[5];
  const float* b3 = (const float*)d_in[6];

  float* out   = (float*)d_out;
  float* A_out = out;
  float* T_out = out + (size_t)NPIX * KK;

  float* phi  = (float*)d_ws;                   // 64 MB, reused as A ping
  float* wb   = phi + (size_t)NPIX * 32;        // 8 MB
  float* part = wb  + (size_t)NPIX * 4;         // ~1 MB

  cnn_kernel<<<dim3(WD/32, HD/16, BB), 512, 0, stream>>>(X, w1, b1, w2, b2, w3, b3, phi);
  aff_kernel<<<NPIX/256, 256, 0, stream>>>(phi, wb);

  float* Aping = phi;  // phi dead after aff_kernel
  mp_kernel<1><<<NPIX/256, 256, 0, stream>>>(A_out, wb, Aping);   // iter 1 (analytic init)
  for (int it = 0; it < 3; it++) {
    mp_kernel<0><<<NPIX/256, 256, 0, stream>>>(Aping, wb, A_out);
    mp_kernel<0><<<NPIX/256, 256, 0, stream>>>(A_out, wb, Aping);
  }
  mp_kernel<0><<<NPIX/256, 256, 0, stream>>>(Aping, wb, A_out);   // iter 8 -> A_out

  pool1_kernel<<<dim3(BB, 16), 256, 0, stream>>>(A_out, X, part);
  pool2_kernel<<<(BB*KK + 255)/256, 256, 0, stream>>>(part, T_out);
}

// Round 3
// 322.762 us; speedup vs baseline: 2.6473x; 2.0537x over previous
//
#include <hip/hip_runtime.h>
#include <math.h>

#define HD 128
#define WD 128
#define BB 32
#define KK 32
#define NPIX (BB*HD*WD)   // 524288

typedef _Float16 f16;
typedef __attribute__((ext_vector_type(8))) _Float16 f16x8;
typedef __attribute__((ext_vector_type(4))) float f32x4;

// byte offset of 16B chunk g within 64B row; bijective over (row mod 8) -> all 32 banks
__device__ __forceinline__ int swz(int row, int g){
  return row*64 + (((g + (row >> 1)) & 3) << 4);
}

// ---------------- fused CNN via f16 MFMA ----------------
// tile 16 rows x 32 cols, 512 threads (8 waves), halo x1 18x34, 2 blocks/CU
__global__ __launch_bounds__(512, 2) void cnn_kernel(
    const int* __restrict__ X,
    const float* __restrict__ w1, const float* __restrict__ b1,
    const float* __restrict__ w2, const float* __restrict__ b2,
    const float* __restrict__ w3, const float* __restrict__ b3,
    f16* __restrict__ phi)
{
  __shared__ float sW1[9*11*36];     // [tap][class(11; 10=zero)][36-pad oc]
  __shared__ int   sX[20*36];
  __shared__ float sB1[32], sB2[32], sB3[32];
  __shared__ f16 x1[612*32];         // halo 18x34 rows x 32 ic, swizzled; reused as y2
  __shared__ f16 w2t[9*32*32];       // [tap*32+oc][ic], swizzled
  __shared__ f16 w3t[32*32];         // [oe][ic], swizzled

  const int tid = threadIdx.x;
  const int img = blockIdx.z;
  const int bh0 = blockIdx.y * 16;
  const int bw0 = blockIdx.x * 32;

  for (int i = tid; i < 9*11*32; i += 512) {
    int tap = i / 352, c = (i % 352) >> 5, oc = i & 31;
    sW1[(tap*11 + c)*36 + oc] = (c < 10) ? w1[tap*320 + c*32 + oc] : 0.f;
  }
  for (int i = tid; i < 9*32*32; i += 512) {
    int tap = i >> 10, ic = (i >> 5) & 31, oc = i & 31;
    int off = swz(tap*32 + oc, ic >> 3) + (ic & 7)*2;
    *(f16*)((char*)w2t + off) = (f16)w2[i];
  }
  for (int i = tid; i < 32*32; i += 512) {
    int ic = i >> 5, oe = i & 31;
    int off = swz(oe, ic >> 3) + (ic & 7)*2;
    *(f16*)((char*)w3t + off) = (f16)w3[i];
  }
  if (tid < 32) { sB1[tid] = b1[tid]; sB2[tid] = b2[tid]; sB3[tid] = b3[tid]; }
  for (int i = tid; i < 20*36; i += 512) {
    int ti = i / 36, tj = i % 36;
    int gh = bh0 - 2 + ti, gw = bw0 - 2 + tj;
    sX[i] = (gh >= 0 && gh < HD && gw >= 0 && gw < WD) ? X[(img*HD + gh)*WD + gw] : 10;
  }
  __syncthreads();

  // conv1: class-gather (exact f32) -> relu -> f16 into x1
  for (int p = tid; p < 612; p += 512) {
    int hr = p / 34, hc = p - hr*34;
    int gh = bh0 + hr - 1, gw = bw0 + hc - 1;
    if (gh >= 0 && gh < HD && gw >= 0 && gw < WD) {
      float a[32];
      #pragma unroll
      for (int g = 0; g < 8; g++) {
        float4 v = ((const float4*)sB1)[g];
        a[4*g] = v.x; a[4*g+1] = v.y; a[4*g+2] = v.z; a[4*g+3] = v.w;
      }
      #pragma unroll
      for (int tap = 0; tap < 9; tap++) {
        const int ti = tap/3, tj = tap%3;
        int c = sX[(hr+ti)*36 + hc + tj];
        const float4* wr = (const float4*)&sW1[(tap*11 + c)*36];
        #pragma unroll
        for (int g = 0; g < 8; g++) {
          float4 v = wr[g];
          a[4*g] += v.x; a[4*g+1] += v.y; a[4*g+2] += v.z; a[4*g+3] += v.w;
        }
      }
      #pragma unroll
      for (int g = 0; g < 4; g++) {
        f16x8 hv;
        #pragma unroll
        for (int j = 0; j < 8; j++) hv[j] = (f16)fmaxf(a[g*8+j], 0.f);
        *(f16x8*)((char*)x1 + swz(p, g)) = hv;
      }
    } else {
      f16x8 z;
      #pragma unroll
      for (int j = 0; j < 8; j++) z[j] = (f16)0.f;
      #pragma unroll
      for (int g = 0; g < 4; g++) *(f16x8*)((char*)x1 + swz(p, g)) = z;
    }
  }
  __syncthreads();

  // conv2 via MFMA
  const int lane = tid & 63;
  const int wv   = tid >> 6;
  const int lr   = lane & 15;
  const int kg   = lane >> 4;
  const int mts  = wv * 4;

  int arow0[4];
  #pragma unroll
  for (int q = 0; q < 4; q++) {
    int px = (mts + q)*16 + lr;
    arow0[q] = (px >> 5)*34 + (px & 31);
  }
  float b2v0 = sB2[lr], b2v1 = sB2[lr + 16];
  f32x4 acc[4][2];
  #pragma unroll
  for (int q = 0; q < 4; q++) {
    acc[q][0] = (f32x4){b2v0, b2v0, b2v0, b2v0};
    acc[q][1] = (f32x4){b2v1, b2v1, b2v1, b2v1};
  }
  #pragma unroll
  for (int tap = 0; tap < 9; tap++) {
    const int ti = tap/3, tj = tap%3;
    f16x8 bf0 = *(const f16x8*)((const char*)w2t + swz(tap*32 + lr,      kg));
    f16x8 bf1 = *(const f16x8*)((const char*)w2t + swz(tap*32 + lr + 16, kg));
    #pragma unroll
    for (int q = 0; q < 4; q++) {
      int row = arow0[q] + ti*34 + tj;
      f16x8 af = *(const f16x8*)((const char*)x1 + swz(row, kg));
      acc[q][0] = __builtin_amdgcn_mfma_f32_16x16x32_f16(af, bf0, acc[q][0], 0, 0, 0);
      acc[q][1] = __builtin_amdgcn_mfma_f32_16x16x32_f16(af, bf1, acc[q][1], 0, 0, 0);
    }
  }
  __syncthreads();

  // relu -> y2 (reuse x1, rows 0..511)
  #pragma unroll
  for (int q = 0; q < 4; q++)
    #pragma unroll
    for (int nt = 0; nt < 2; nt++) {
      int oc = nt*16 + lr;
      #pragma unroll
      for (int rg = 0; rg < 4; rg++) {
        int px = (mts + q)*16 + kg*4 + rg;
        int off = swz(px, oc >> 3) + (oc & 7)*2;
        *(f16*)((char*)x1 + off) = (f16)fmaxf(acc[q][nt][rg], 0.f);
      }
    }
  __syncthreads();

  // conv3 via MFMA + write phi (f16)
  {
    f16x8 cf0 = *(const f16x8*)((const char*)w3t + swz(lr,      kg));
    f16x8 cf1 = *(const f16x8*)((const char*)w3t + swz(lr + 16, kg));
    float b3v0 = sB3[lr], b3v1 = sB3[lr + 16];
    #pragma unroll
    for (int q = 0; q < 4; q++) {
      f16x8 af = *(const f16x8*)((const char*)x1 + swz((mts + q)*16 + lr, kg));
      f32x4 o0 = (f32x4){b3v0, b3v0, b3v0, b3v0};
      f32x4 o1 = (f32x4){b3v1, b3v1, b3v1, b3v1};
      o0 = __builtin_amdgcn_mfma_f32_16x16x32_f16(af, cf0, o0, 0, 0, 0);
      o1 = __builtin_amdgcn_mfma_f32_16x16x32_f16(af, cf1, o1, 0, 0, 0);
      #pragma unroll
      for (int rg = 0; rg < 4; rg++) {
        int px = (mts + q)*16 + kg*4 + rg;
        int gh = bh0 + (px >> 5), gw = bw0 + (px & 31);
        f16* dst = phi + ((size_t)((img*HD + gh)*WD + gw))*32;
        dst[lr]      = (f16)o0[rg];
        dst[lr + 16] = (f16)o1[rg];
      }
    }
  }
}

// ---------------- neighbor affinity from f16 phi ----------------
__device__ __forceinline__ float aff_one(const f16x8* __restrict__ nb,
                                         f16x8 c0, f16x8 c1, f16x8 c2, f16x8 c3,
                                         bool valid) {
  if (!valid) return 0.f;
  f16x8 d0 = c0 - nb[0]; f16x8 s = d0*d0;
  f16x8 d1 = c1 - nb[1]; s += d1*d1;
  f16x8 d2 = c2 - nb[2]; s += d2*d2;
  f16x8 d3 = c3 - nb[3]; s += d3*d3;
  float d2f = 0.f;
  #pragma unroll
  for (int j = 0; j < 8; j++) d2f += (float)s[j];
  return __expf(-2.f * d2f);
}

__global__ __launch_bounds__(256) void aff_kernel(const f16* __restrict__ phi, float* __restrict__ wb) {
  const int t = blockIdx.x * 256 + threadIdx.x;
  const int w = t & (WD-1), h = (t >> 7) & (HD-1);
  const f16x8* pc = (const f16x8*)(phi + (size_t)t * 32);
  f16x8 c0 = pc[0], c1 = pc[1], c2 = pc[2], c3 = pc[3];
  float4 out;
  out.x = aff_one(pc + WD*4, c0,c1,c2,c3, h < HD-1);
  out.y = aff_one(pc - WD*4, c0,c1,c2,c3, h > 0);
  out.z = aff_one(pc + 4,    c0,c1,c2,c3, w < WD-1);
  out.w = aff_one(pc - 4,    c0,c1,c2,c3, w > 0);
  ((float4*)wb)[t] = out;
}

// ---------------- A0 table (batch-independent): 128x128x32 f16 ----------------
__global__ __launch_bounds__(256) void init0_kernel(f16* __restrict__ A0) {
  const int t = blockIdx.x * 256 + threadIdx.x;   // 16384
  const float fh = (float)(t >> 7), fw = (float)(t & 127);
  float e[32]; float s = 0.f;
  #pragma unroll
  for (int kh = 0; kh < 4; kh++) {
    float dh = fh - (float)(kh*32 + 16);
    float dh2 = dh*dh;
    #pragma unroll
    for (int kw = 0; kw < 8; kw++) {
      float dw = fw - (float)(kw*16 + 8);
      float x = __expf(-(dh2 + dw*dw) * (1.f/512.f));
      e[kh*8+kw] = x; s += x;
    }
  }
  float inv = 1.f / s;
  f16x8* dst = (f16x8*)(A0 + (size_t)t*32);
  #pragma unroll
  for (int q = 0; q < 4; q++) {
    f16x8 o;
    #pragma unroll
    for (int j = 0; j < 8; j++) o[j] = (f16)(e[q*8+j]*inv);
    dst[q] = o;
  }
}

// ---------------- message pass: A = softmax_k(2 * sum_d w_d * A_nb) ----------------
__device__ __forceinline__ void acc_dir(f16x8* agg, const f16* __restrict__ src, float wt) {
  const f16x8* s = (const f16x8*)src;
  f16 wh = (f16)wt;
  f16x8 wv;
  #pragma unroll
  for (int j = 0; j < 8; j++) wv[j] = wh;
  #pragma unroll
  for (int q = 0; q < 4; q++) agg[q] += s[q] * wv;
}

template<int IN_A0, int OUT_F32>
__global__ __launch_bounds__(256) void mp_kernel(const f16* __restrict__ Ain,
                                                 const float* __restrict__ wb,
                                                 f16* __restrict__ Aout,
                                                 float* __restrict__ AoutF) {
  const int blk  = blockIdx.x;
  const int sblk = (blk & 7) * 256 + (blk >> 3);   // 256 contiguous blocks per XCD
  const int t = sblk * 256 + threadIdx.x;
  const int w = t & (WD-1), h = (t >> 7) & (HD-1);
  float4 wd = ((const float4*)wb)[t];

  int iu, id, il, ir;
  if (IN_A0) {
    int p = h*WD + w;
    iu = (h < HD-1) ? p + WD : p;
    id = (h > 0)    ? p - WD : p;
    il = (w < WD-1) ? p + 1  : p;
    ir = (w > 0)    ? p - 1  : p;
  } else {
    iu = (h < HD-1) ? t + WD : t;
    id = (h > 0)    ? t - WD : t;
    il = (w < WD-1) ? t + 1  : t;
    ir = (w > 0)    ? t - 1  : t;
  }

  f16x8 agg[4];
  #pragma unroll
  for (int q = 0; q < 4; q++)
    #pragma unroll
    for (int j = 0; j < 8; j++) agg[q][j] = (f16)0.f;

  acc_dir(agg, Ain + (size_t)iu*32, wd.x);
  acc_dir(agg, Ain + (size_t)id*32, wd.y);
  acc_dir(agg, Ain + (size_t)il*32, wd.z);
  acc_dir(agg, Ain + (size_t)ir*32, wd.w);

  float a[32];
  #pragma unroll
  for (int q = 0; q < 4; q++)
    #pragma unroll
    for (int j = 0; j < 8; j++) a[q*8+j] = (float)agg[q][j];

  float s = 0.f;
  #pragma unroll
  for (int k = 0; k < 32; k++) { a[k] = __expf(a[k] + a[k]); s += a[k]; }   // 2*agg <= 8, no max needed
  float inv = 1.f / s;

  if (OUT_F32) {
    float4* dst = (float4*)(AoutF + (size_t)t*32);
    #pragma unroll
    for (int q = 0; q < 8; q++)
      dst[q] = make_float4(a[4*q]*inv, a[4*q+1]*inv, a[4*q+2]*inv, a[4*q+3]*inv);
  } else {
    f16x8* dst = (f16x8*)(Aout + (size_t)t*32);
    #pragma unroll
    for (int q = 0; q < 4; q++) {
      f16x8 o;
      #pragma unroll
      for (int j = 0; j < 8; j++) o[j] = (f16)(a[q*8+j]*inv);
      dst[q] = o;
    }
  }
}

// ---------------- pooled features, stage 1: per-(b, 4-row x half-width) partials ----------------
__global__ __launch_bounds__(256) void pool1_kernel(const float* __restrict__ A,
                                                    const int* __restrict__ X,
                                                    float* __restrict__ part) {
  const int b = blockIdx.x, cy = blockIdx.y;       // cy: 0..31 (4-row chunks)
  const int k = threadIdx.x & 31, sub = threadIdx.x >> 5;  // sub: (row in chunk)*2 + whalf
  const int h = cy*4 + (sub >> 1);
  const int w0 = (sub & 1) * 64;
  const float hh = ((float)h + 0.5f) * (1.f/128.f);
  float s0 = 0.f, sw = 0.f, sw2 = 0.f;
  float col[10];
  #pragma unroll
  for (int c = 0; c < 10; c++) col[c] = 0.f;
  const float* Arow = A + ((size_t)((b*HD + h)*WD + w0))*32 + k;
  const int*   Xrow = X + (b*HD + h)*WD + w0;
  for (int w = 0; w < 64; w++) {
    float a  = Arow[(size_t)w*32];
    float ww = ((float)(w + w0) + 0.5f) * (1.f/128.f);
    s0 += a; sw = fmaf(ww, a, sw); sw2 = fmaf(ww*ww, a, sw2);
    int x = Xrow[w];
    #pragma unroll
    for (int c = 0; c < 10; c++) col[c] += (x == c) ? a : 0.f;
  }
  __shared__ float red[8][32][15];
  float vals[15];
  vals[0] = s0; vals[1] = hh*s0; vals[2] = sw; vals[3] = hh*hh*s0; vals[4] = sw2;
  #pragma unroll
  for (int c = 0; c < 10; c++) vals[5+c] = col[c];
  #pragma unroll
  for (int q = 0; q < 15; q++) red[sub][k][q] = vals[q];
  __syncthreads();
  if (sub == 0) {
    #pragma unroll
    for (int q = 0; q < 15; q++) {
      float v = 0.f;
      #pragma unroll
      for (int s2 = 0; s2 < 8; s2++) v += red[s2][k][q];
      part[(((size_t)b*32 + cy)*32 + k)*15 + q] = v;
    }
  }
}

// ---------------- pooled features, stage 2 ----------------
__global__ __launch_bounds__(256) void pool2_kernel(const float* __restrict__ part,
                                                    float* __restrict__ T) {
  const int t = blockIdx.x * 256 + threadIdx.x;
  if (t >= BB*KK) return;
  const int b = t >> 5, k = t & 31;
  float s[15];
  #pragma unroll
  for (int q = 0; q < 15; q++) s[q] = 0.f;
  for (int cy = 0; cy < 32; cy++) {
    const float* p = part + (((size_t)b*32 + cy)*32 + k)*15;
    #pragma unroll
    for (int q = 0; q < 15; q++) s[q] += p[q];
  }
  float mass = s[0] + 1e-6f;
  float inv  = 1.f / mass;
  float h_c = s[1]*inv, w_c = s[2]*inv, h2 = s[3]*inv, w2 = s[4]*inv;
  float h_sd = sqrtf(fmaxf(h2 - h_c*h_c, 0.f) + 1e-6f);
  float w_sd = sqrtf(fmaxf(w2 - w_c*w_c, 0.f) + 1e-6f);
  float* o = T + (size_t)t*17;
  o[0] = mass * (1.f/16384.f);
  o[1] = h_c; o[2] = w_c;
  #pragma unroll
  for (int c = 0; c < 10; c++) o[3+c] = s[5+c]*inv;
  o[13] = h_c - h_sd; o[14] = h_c + h_sd; o[15] = w_c - w_sd; o[16] = w_c + w_sd;
}

extern "C" void kernel_launch(void* const* d_in, const int* in_sizes, int n_in,
                              void* d_out, int out_size, void* d_ws, size_t ws_size,
                              hipStream_t stream) {
  const int*   X  = (const int*)d_in[0];
  const float* w1 = (const float*)d_in[1];
  const float* b1 = (const float*)d_in[2];
  const float* w2 = (const float*)d_in[3];
  const float* b2 = (const float*)d_in[4];
  const float* w3 = (const float*)d_in[5];
  const float* b3 = (const float*)d_in[6];

  float* out   = (float*)d_out;
  float* A_out = out;                           // (B,H,W,K) f32
  float* T_out = out + (size_t)NPIX * KK;       // (B,K,17)

  char*  ws   = (char*)d_ws;
  f16*   bufA = (f16*)ws;                                   // 32 MB: phi, then A ping
  float* wb   = (float*)(ws + (size_t)32*1024*1024);        // 8 MB
  f16*   bufB = (f16*)(ws + (size_t)40*1024*1024);          // 32 MB: A0 table, then A pong
  float* part = (float*)(ws + (size_t)40*1024*1024);        // reuses bufB after mp done

  cnn_kernel<<<dim3(WD/32, HD/16, BB), 512, 0, stream>>>(X, w1, b1, w2, b2, w3, b3, bufA);
  aff_kernel<<<NPIX/256, 256, 0, stream>>>(bufA, wb);
  init0_kernel<<<HD*WD/256, 256, 0, stream>>>(bufB);        // A0 (16384 px, batch-free)

  mp_kernel<1,0><<<NPIX/256, 256, 0, stream>>>(bufB, wb, bufA, nullptr);  // it1: A0 -> A
  for (int it = 0; it < 3; it++) {
    mp_kernel<0,0><<<NPIX/256, 256, 0, stream>>>(bufA, wb, bufB, nullptr);
    mp_kernel<0,0><<<NPIX/256, 256, 0, stream>>>(bufB, wb, bufA, nullptr);
  }
  mp_kernel<0,1><<<NPIX/256, 256, 0, stream>>>(bufA, wb, nullptr, A_out); // it8 -> f32 out

  pool1_kernel<<<dim3(BB, 32), 256, 0, stream>>>(A_out, X, part);
  pool2_kernel<<<(BB*KK + 255)/256, 256, 0, stream>>>(part, T_out);
}

// Round 4
// 287.716 us; speedup vs baseline: 2.9697x; 1.1218x over previous
//
#include <hip/hip_runtime.h>
#include <math.h>

#define HD 128
#define WD 128
#define BB 32
#define KK 32
#define NPIX (BB*HD*WD)   // 524288

typedef _Float16 f16;
typedef __attribute__((ext_vector_type(8))) _Float16 f16x8;
typedef __attribute__((ext_vector_type(4))) float f32x4;

// byte offset of 16B chunk g within 64B row; bijective over (row mod 8) -> all 32 banks
__device__ __forceinline__ int swz(int row, int g){
  return row*64 + (((g + (row >> 1)) & 3) << 4);
}

// ---------------- fused CNN via f16 MFMA ----------------
// tile 16 rows x 32 cols, 512 threads (8 waves), halo x1 18x34, 2 blocks/CU
__global__ __launch_bounds__(512, 2) void cnn_kernel(
    const int* __restrict__ X,
    const float* __restrict__ w1, const float* __restrict__ b1,
    const float* __restrict__ w2, const float* __restrict__ b2,
    const float* __restrict__ w3, const float* __restrict__ b3,
    f16* __restrict__ phi)
{
  __shared__ f16 sW1f[9*11*40];      // [tap][class(11; 10=zero)][40-pad oc], bias folded into tap4
  __shared__ int   sX[20*36];
  __shared__ float sB2[32], sB3[32];
  __shared__ f16 x1[612*32];         // halo 18x34 rows x 32 ic, swizzled; reused as y2
  __shared__ f16 w2t[9*32*32];       // [tap*32+oc][ic], swizzled
  __shared__ f16 w3t[32*32];         // [oe][ic], swizzled

  const int tid = threadIdx.x;
  const int img = blockIdx.z;
  const int bh0 = blockIdx.y * 16;
  const int bw0 = blockIdx.x * 32;

  for (int i = tid; i < 9*11*32; i += 512) {
    int tap = i / 352, c = (i % 352) >> 5, oc = i & 31;
    float v = (c < 10) ? w1[tap*320 + c*32 + oc] : 0.f;
    if (tap == 4 && c < 10) v += b1[oc];
    sW1f[(tap*11 + c)*40 + oc] = (f16)v;
  }
  for (int i = tid; i < 9*32*32; i += 512) {
    int tap = i >> 10, ic = (i >> 5) & 31, oc = i & 31;
    int off = swz(tap*32 + oc, ic >> 3) + (ic & 7)*2;
    *(f16*)((char*)w2t + off) = (f16)w2[i];
  }
  for (int i = tid; i < 32*32; i += 512) {
    int ic = i >> 5, oe = i & 31;
    int off = swz(oe, ic >> 3) + (ic & 7)*2;
    *(f16*)((char*)w3t + off) = (f16)w3[i];
  }
  if (tid < 32) { sB2[tid] = b2[tid]; sB3[tid] = b3[tid]; }
  for (int i = tid; i < 20*36; i += 512) {
    int ti = i / 36, tj = i % 36;
    int gh = bh0 - 2 + ti, gw = bw0 - 2 + tj;
    sX[i] = (gh >= 0 && gh < HD && gw >= 0 && gw < WD) ? X[(img*HD + gh)*WD + gw] : 10;
  }
  __syncthreads();

  // conv1: packed-f16 class-row gather -> relu -> x1 (swizzled)
  for (int p = tid; p < 612; p += 512) {
    int hr = p / 34, hc = p - hr*34;
    int gh = bh0 + hr - 1, gw = bw0 + hc - 1;
    if (gh >= 0 && gh < HD && gw >= 0 && gw < WD) {
      f16x8 acc[4];
      {
        int c = sX[hr*36 + hc];   // tap 0
        const f16* wr = &sW1f[c*40];
        #pragma unroll
        for (int g = 0; g < 4; g++) acc[g] = *(const f16x8*)(wr + g*8);
      }
      #pragma unroll
      for (int tap = 1; tap < 9; tap++) {
        const int ti = tap/3, tj = tap%3;
        int c = sX[(hr+ti)*36 + hc + tj];
        const f16* wr = &sW1f[(tap*11 + c)*40];
        #pragma unroll
        for (int g = 0; g < 4; g++) acc[g] += *(const f16x8*)(wr + g*8);
      }
      f16x8 z;
      #pragma unroll
      for (int j = 0; j < 8; j++) z[j] = (f16)0.f;
      #pragma unroll
      for (int g = 0; g < 4; g++) {
        f16x8 r = acc[g];
        #pragma unroll
        for (int j = 0; j < 8; j++) r[j] = (r[j] > (f16)0.f) ? r[j] : (f16)0.f;
        *(f16x8*)((char*)x1 + swz(p, g)) = r;
      }
    } else {
      f16x8 z;
      #pragma unroll
      for (int j = 0; j < 8; j++) z[j] = (f16)0.f;
      #pragma unroll
      for (int g = 0; g < 4; g++) *(f16x8*)((char*)x1 + swz(p, g)) = z;
    }
  }
  __syncthreads();

  // conv2 via MFMA
  const int lane = tid & 63;
  const int wv   = tid >> 6;
  const int lr   = lane & 15;
  const int kg   = lane >> 4;
  const int mts  = wv * 4;

  int arow0[4];
  #pragma unroll
  for (int q = 0; q < 4; q++) {
    int px = (mts + q)*16 + lr;
    arow0[q] = (px >> 5)*34 + (px & 31);
  }
  float b2v0 = sB2[lr], b2v1 = sB2[lr + 16];
  f32x4 acc[4][2];
  #pragma unroll
  for (int q = 0; q < 4; q++) {
    acc[q][0] = (f32x4){b2v0, b2v0, b2v0, b2v0};
    acc[q][1] = (f32x4){b2v1, b2v1, b2v1, b2v1};
  }
  #pragma unroll
  for (int tap = 0; tap < 9; tap++) {
    const int ti = tap/3, tj = tap%3;
    f16x8 bf0 = *(const f16x8*)((const char*)w2t + swz(tap*32 + lr,      kg));
    f16x8 bf1 = *(const f16x8*)((const char*)w2t + swz(tap*32 + lr + 16, kg));
    #pragma unroll
    for (int q = 0; q < 4; q++) {
      int row = arow0[q] + ti*34 + tj;
      f16x8 af = *(const f16x8*)((const char*)x1 + swz(row, kg));
      acc[q][0] = __builtin_amdgcn_mfma_f32_16x16x32_f16(af, bf0, acc[q][0], 0, 0, 0);
      acc[q][1] = __builtin_amdgcn_mfma_f32_16x16x32_f16(af, bf1, acc[q][1], 0, 0, 0);
    }
  }
  __syncthreads();

  // relu -> y2 (reuse x1, rows 0..511)
  #pragma unroll
  for (int q = 0; q < 4; q++)
    #pragma unroll
    for (int nt = 0; nt < 2; nt++) {
      int oc = nt*16 + lr;
      #pragma unroll
      for (int rg = 0; rg < 4; rg++) {
        int px = (mts + q)*16 + kg*4 + rg;
        int off = swz(px, oc >> 3) + (oc & 7)*2;
        *(f16*)((char*)x1 + off) = (f16)fmaxf(acc[q][nt][rg], 0.f);
      }
    }
  __syncthreads();

  // conv3 via MFMA + write phi (f16)
  {
    f16x8 cf0 = *(const f16x8*)((const char*)w3t + swz(lr,      kg));
    f16x8 cf1 = *(const f16x8*)((const char*)w3t + swz(lr + 16, kg));
    float b3v0 = sB3[lr], b3v1 = sB3[lr + 16];
    #pragma unroll
    for (int q = 0; q < 4; q++) {
      f16x8 af = *(const f16x8*)((const char*)x1 + swz((mts + q)*16 + lr, kg));
      f32x4 o0 = (f32x4){b3v0, b3v0, b3v0, b3v0};
      f32x4 o1 = (f32x4){b3v1, b3v1, b3v1, b3v1};
      o0 = __builtin_amdgcn_mfma_f32_16x16x32_f16(af, cf0, o0, 0, 0, 0);
      o1 = __builtin_amdgcn_mfma_f32_16x16x32_f16(af, cf1, o1, 0, 0, 0);
      #pragma unroll
      for (int rg = 0; rg < 4; rg++) {
        int px = (mts + q)*16 + kg*4 + rg;
        int gh = bh0 + (px >> 5), gw = bw0 + (px & 31);
        f16* dst = phi + ((size_t)((img*HD + gh)*WD + gw))*32;
        dst[lr]      = (f16)o0[rg];
        dst[lr + 16] = (f16)o1[rg];
      }
    }
  }
}

// ---------------- neighbor affinity from f16 phi ----------------
__device__ __forceinline__ float aff_one(const f16x8* __restrict__ nb,
                                         f16x8 c0, f16x8 c1, f16x8 c2, f16x8 c3,
                                         bool valid) {
  if (!valid) return 0.f;
  f16x8 d0 = c0 - nb[0]; f16x8 s = d0*d0;
  f16x8 d1 = c1 - nb[1]; s += d1*d1;
  f16x8 d2 = c2 - nb[2]; s += d2*d2;
  f16x8 d3 = c3 - nb[3]; s += d3*d3;
  float d2f = 0.f;
  #pragma unroll
  for (int j = 0; j < 8; j++) d2f += (float)s[j];
  return __expf(-2.f * d2f);
}

__global__ __launch_bounds__(256) void aff_kernel(const f16* __restrict__ phi, float* __restrict__ wb) {
  const int t = blockIdx.x * 256 + threadIdx.x;
  const int w = t & (WD-1), h = (t >> 7) & (HD-1);
  const f16x8* pc = (const f16x8*)(phi + (size_t)t * 32);
  f16x8 c0 = pc[0], c1 = pc[1], c2 = pc[2], c3 = pc[3];
  float4 out;
  out.x = aff_one(pc + WD*4, c0,c1,c2,c3, h < HD-1);
  out.y = aff_one(pc - WD*4, c0,c1,c2,c3, h > 0);
  out.z = aff_one(pc + 4,    c0,c1,c2,c3, w < WD-1);
  out.w = aff_one(pc - 4,    c0,c1,c2,c3, w > 0);
  ((float4*)wb)[t] = out;
}

// ---------------- analytic A0 accumulate: a += wt * softmax_k(-d2/512) at (hh,ww) ----------------
__device__ __forceinline__ void a0_accum(float* a, int hh, int ww, float wt) {
  const float fh = (float)hh, fw = (float)ww;
  float e[32]; float s = 0.f;
  #pragma unroll
  for (int kh = 0; kh < 4; kh++) {
    float dh = fh - (float)(kh*32 + 16);
    float dh2 = dh*dh;
    #pragma unroll
    for (int kw = 0; kw < 8; kw++) {
      float dw = fw - (float)(kw*16 + 8);
      float x = __expf(-(dh2 + dw*dw) * (1.f/512.f));
      e[kh*8+kw] = x; s += x;
    }
  }
  float sc = wt / s;
  #pragma unroll
  for (int k = 0; k < 32; k++) a[k] = fmaf(e[k], sc, a[k]);
}

// ---------------- fused pair of message-pass iterations ----------------
// grid 1024 blocks (XCD-grouped by image), 256 threads; tile 16x32, A_mid (18x34) in LDS
template<int FIRST, int LAST>
__global__ __launch_bounds__(256, 4) void mp2_kernel(const f16* __restrict__ Ain,
                                                     const float* __restrict__ wb,
                                                     f16* __restrict__ Aout,
                                                     float* __restrict__ AoutF) {
  __shared__ f16 amid[612*32];   // 18x34 px, swizzled rows

  const int blk  = blockIdx.x;
  const int cxcd = blk & 7;
  const int q    = blk >> 3;
  const int tile = q & 31;
  const int img  = cxcd + ((q >> 5) << 3);
  const int th0  = (tile >> 2) * 16;
  const int tw0  = (tile & 3) * 32;
  const size_t ibase = (size_t)img * HD * WD;

  // ---- iter a: A_mid at 18x34 (1-px halo) ----
  for (int p = threadIdx.x; p < 612; p += 256) {
    int r = p / 34, cc = p - r*34;
    int gh = th0 - 1 + r, gw = tw0 - 1 + cc;
    bool inimg = (gh >= 0 && gh < HD && gw >= 0 && gw < WD);
    int ghc = min(max(gh, 0), HD-1), gwc = min(max(gw, 0), WD-1);
    float4 wd = make_float4(0.f, 0.f, 0.f, 0.f);
    if (inimg) wd = ((const float4*)wb)[ibase + gh*WD + gw];

    int hu = (ghc < HD-1) ? ghc+1 : ghc;
    int hd = (ghc > 0)    ? ghc-1 : ghc;
    int wl = (gwc < WD-1) ? gwc+1 : gwc;
    int wr = (gwc > 0)    ? gwc-1 : gwc;

    float a[32];
    #pragma unroll
    for (int k = 0; k < 32; k++) a[k] = 0.f;

    if (FIRST) {
      a0_accum(a, hu, gwc, wd.x);
      a0_accum(a, hd, gwc, wd.y);
      a0_accum(a, ghc, wl, wd.z);
      a0_accum(a, ghc, wr, wd.w);
    } else {
      f16x8 agg[4];
      #pragma unroll
      for (int g = 0; g < 4; g++)
        #pragma unroll
        for (int j = 0; j < 8; j++) agg[g][j] = (f16)0.f;
      const size_t i0 = ibase + (size_t)hu*WD + gwc;
      const size_t i1 = ibase + (size_t)hd*WD + gwc;
      const size_t i2 = ibase + (size_t)ghc*WD + wl;
      const size_t i3 = ibase + (size_t)ghc*WD + wr;
      const f16x8* s0 = (const f16x8*)(Ain + i0*32);
      const f16x8* s1 = (const f16x8*)(Ain + i1*32);
      const f16x8* s2 = (const f16x8*)(Ain + i2*32);
      const f16x8* s3 = (const f16x8*)(Ain + i3*32);
      f16 w0 = (f16)wd.x, w1 = (f16)wd.y, w2 = (f16)wd.z, w3 = (f16)wd.w;
      #pragma unroll
      for (int g = 0; g < 4; g++) {
        f16x8 v0 = s0[g], v1 = s1[g], v2 = s2[g], v3 = s3[g];
        #pragma unroll
        for (int j = 0; j < 8; j++)
          agg[g][j] = v0[j]*w0 + v1[j]*w1 + v2[j]*w2 + v3[j]*w3;
      }
      #pragma unroll
      for (int g = 0; g < 4; g++)
        #pragma unroll
        for (int j = 0; j < 8; j++) a[g*8+j] = (float)agg[g][j];
    }

    float s = 0.f;
    #pragma unroll
    for (int k = 0; k < 32; k++) { a[k] = __expf(a[k] + a[k]); s += a[k]; }
    float inv = 1.f / s;
    #pragma unroll
    for (int g = 0; g < 4; g++) {
      f16x8 o;
      #pragma unroll
      for (int j = 0; j < 8; j++) o[j] = (f16)(a[g*8+j] * inv);
      *(f16x8*)((char*)amid + swz(p, g)) = o;
    }
  }
  __syncthreads();

  // ---- iter b: interior 16x32, read A_mid from LDS ----
  for (int p = threadIdx.x; p < 512; p += 256) {
    int r2 = p >> 5, c2 = p & 31;
    int gh = th0 + r2, gw = tw0 + c2;
    int rm = r2 + 1, cm = c2 + 1;
    float4 wd = ((const float4*)wb)[ibase + gh*WD + gw];

    int ru = rm + ((gh < HD-1) ? 1 : 0);
    int rd = rm - ((gh > 0)    ? 1 : 0);
    int cl = cm + ((gw < WD-1) ? 1 : 0);
    int cr = cm - ((gw > 0)    ? 1 : 0);
    int p0 = ru*34 + cm, p1 = rd*34 + cm, p2 = rm*34 + cl, p3 = rm*34 + cr;

    f16 w0 = (f16)wd.x, w1 = (f16)wd.y, w2 = (f16)wd.z, w3 = (f16)wd.w;
    float a[32];
    #pragma unroll
    for (int g = 0; g < 4; g++) {
      f16x8 v0 = *(const f16x8*)((const char*)amid + swz(p0, g));
      f16x8 v1 = *(const f16x8*)((const char*)amid + swz(p1, g));
      f16x8 v2 = *(const f16x8*)((const char*)amid + swz(p2, g));
      f16x8 v3 = *(const f16x8*)((const char*)amid + swz(p3, g));
      #pragma unroll
      for (int j = 0; j < 8; j++) {
        f16 x = v0[j]*w0 + v1[j]*w1 + v2[j]*w2 + v3[j]*w3;
        a[g*8+j] = (float)x;
      }
    }
    float s = 0.f;
    #pragma unroll
    for (int k = 0; k < 32; k++) { a[k] = __expf(a[k] + a[k]); s += a[k]; }
    float inv = 1.f / s;
    size_t opix = ibase + (size_t)gh*WD + gw;
    if (LAST) {
      float4* dst = (float4*)(AoutF + opix*32);
      #pragma unroll
      for (int g = 0; g < 8; g++)
        dst[g] = make_float4(a[4*g]*inv, a[4*g+1]*inv, a[4*g+2]*inv, a[4*g+3]*inv);
    } else {
      f16x8* dst = (f16x8*)(Aout + opix*32);
      #pragma unroll
      for (int g = 0; g < 4; g++) {
        f16x8 o;
        #pragma unroll
        for (int j = 0; j < 8; j++) o[j] = (f16)(a[g*8+j]*inv);
        dst[g] = o;
      }
    }
  }
}

// ---------------- pooled features, stage 1 ----------------
__global__ __launch_bounds__(256) void pool1_kernel(const float* __restrict__ A,
                                                    const int* __restrict__ X,
                                                    float* __restrict__ part) {
  const int b = blockIdx.x, cy = blockIdx.y;
  const int k = threadIdx.x & 31, sub = threadIdx.x >> 5;
  const int h = cy*4 + (sub >> 1);
  const int w0 = (sub & 1) * 64;
  const float hh = ((float)h + 0.5f) * (1.f/128.f);
  float s0 = 0.f, sw = 0.f, sw2 = 0.f;
  float col[10];
  #pragma unroll
  for (int c = 0; c < 10; c++) col[c] = 0.f;
  const float* Arow = A + ((size_t)((b*HD + h)*WD + w0))*32 + k;
  const int*   Xrow = X + (b*HD + h)*WD + w0;
  for (int w = 0; w < 64; w++) {
    float a  = Arow[(size_t)w*32];
    float ww = ((float)(w + w0) + 0.5f) * (1.f/128.f);
    s0 += a; sw = fmaf(ww, a, sw); sw2 = fmaf(ww*ww, a, sw2);
    int x = Xrow[w];
    #pragma unroll
    for (int c = 0; c < 10; c++) col[c] += (x == c) ? a : 0.f;
  }
  __shared__ float red[8][32][15];
  float vals[15];
  vals[0] = s0; vals[1] = hh*s0; vals[2] = sw; vals[3] = hh*hh*s0; vals[4] = sw2;
  #pragma unroll
  for (int c = 0; c < 10; c++) vals[5+c] = col[c];
  #pragma unroll
  for (int q = 0; q < 15; q++) red[sub][k][q] = vals[q];
  __syncthreads();
  if (sub == 0) {
    #pragma unroll
    for (int q = 0; q < 15; q++) {
      float v = 0.f;
      #pragma unroll
      for (int s2 = 0; s2 < 8; s2++) v += red[s2][k][q];
      part[(((size_t)b*32 + cy)*32 + k)*15 + q] = v;
    }
  }
}

// ---------------- pooled features, stage 2 ----------------
__global__ __launch_bounds__(256) void pool2_kernel(const float* __restrict__ part,
                                                    float* __restrict__ T) {
  const int t = blockIdx.x * 256 + threadIdx.x;
  if (t >= BB*KK) return;
  const int b = t >> 5, k = t & 31;
  float s[15];
  #pragma unroll
  for (int q = 0; q < 15; q++) s[q] = 0.f;
  for (int cy = 0; cy < 32; cy++) {
    const float* p = part + (((size_t)b*32 + cy)*32 + k)*15;
    #pragma unroll
    for (int q = 0; q < 15; q++) s[q] += p[q];
  }
  float mass = s[0] + 1e-6f;
  float inv  = 1.f / mass;
  float h_c = s[1]*inv, w_c = s[2]*inv, h2 = s[3]*inv, w2 = s[4]*inv;
  float h_sd = sqrtf(fmaxf(h2 - h_c*h_c, 0.f) + 1e-6f);
  float w_sd = sqrtf(fmaxf(w2 - w_c*w_c, 0.f) + 1e-6f);
  float* o = T + (size_t)t*17;
  o[0] = mass * (1.f/16384.f);
  o[1] = h_c; o[2] = w_c;
  #pragma unroll
  for (int c = 0; c < 10; c++) o[3+c] = s[5+c]*inv;
  o[13] = h_c - h_sd; o[14] = h_c + h_sd; o[15] = w_c - w_sd; o[16] = w_c + w_sd;
}

extern "C" void kernel_launch(void* const* d_in, const int* in_sizes, int n_in,
                              void* d_out, int out_size, void* d_ws, size_t ws_size,
                              hipStream_t stream) {
  const int*   X  = (const int*)d_in[0];
  const float* w1 = (const float*)d_in[1];
  const float* b1 = (const float*)d_in[2];
  const float* w2 = (const float*)d_in[3];
  const float* b2 = (const float*)d_in[4];
  const float* w3 = (const float*)d_in[5];
  const float* b3 = (const float*)d_in[6];

  float* out   = (float*)d_out;
  float* A_out = out;                           // (B,H,W,K) f32
  float* T_out = out + (size_t)NPIX * KK;       // (B,K,17)

  char*  ws   = (char*)d_ws;
  f16*   bufA = (f16*)ws;                                   // 32 MB: A ping (also part later)
  float* wb   = (float*)(ws + (size_t)32*1024*1024);        // 8 MB
  f16*   bufB = (f16*)(ws + (size_t)40*1024*1024);          // 32 MB: phi, then A pong
  float* part = (float*)ws;                                 // aliases bufA (dead at pool time)

  f16* phi = bufB;
  cnn_kernel<<<dim3(WD/32, HD/16, BB), 512, 0, stream>>>(X, w1, b1, w2, b2, w3, b3, phi);
  aff_kernel<<<NPIX/256, 256, 0, stream>>>(phi, wb);

  mp2_kernel<1,0><<<1024, 256, 0, stream>>>(nullptr, wb, bufA, nullptr);  // iters 1,2 (analytic A0)
  mp2_kernel<0,0><<<1024, 256, 0, stream>>>(bufA, wb, bufB, nullptr);     // iters 3,4
  mp2_kernel<0,0><<<1024, 256, 0, stream>>>(bufB, wb, bufA, nullptr);     // iters 5,6
  mp2_kernel<0,1><<<1024, 256, 0, stream>>>(bufA, wb, nullptr, A_out);    // iters 7,8 -> f32

  pool1_kernel<<<dim3(BB, 32), 256, 0, stream>>>(A_out, X, part);
  pool2_kernel<<<(BB*KK + 255)/256, 256, 0, stream>>>(part, T_out);
}